// Round 13
// baseline (340.617 us; speedup 1.0000x reference)
//
#include <hip/hip_runtime.h>
#include <math.h>

#define N_NODES 100000
#define NREL 2
#define BATCH_MAX 4096
#define BSHIFT 8
#define NBUCK ((N_NODES + 255) >> 8)   // 391
#define EPB 2048                       // edges per block in hist/binB (parallelism > burst length)
#define NBX 12500                      // tobf16 blocks: N*128/4/256
#define NZB 391                        // zero-mark blocks

typedef __attribute__((ext_vector_type(8))) short bf16x8;
typedef __attribute__((ext_vector_type(4))) float f32x4;

__device__ inline ushort f2bf(float f) {
    unsigned u = __float_as_uint(f);
    u += 0x7FFF + ((u >> 16) & 1);
    return (ushort)(u >> 16);
}
__device__ inline unsigned pk2(float lo, float hi) {
    return ((unsigned)f2bf(lo)) | (((unsigned)f2bf(hi)) << 16);
}

// unpack uint4 (8 bf16) and accumulate into a0[8]/a1[8] by relation bit (p>>28)
#define UNPACK_ACC(p, U)                                            \
    {                                                               \
        float f0 = __uint_as_float((U).x << 16);                    \
        float f1 = __uint_as_float((U).x & 0xFFFF0000u);            \
        float f2 = __uint_as_float((U).y << 16);                    \
        float f3 = __uint_as_float((U).y & 0xFFFF0000u);            \
        float f4 = __uint_as_float((U).z << 16);                    \
        float f5 = __uint_as_float((U).z & 0xFFFF0000u);            \
        float f6 = __uint_as_float((U).w << 16);                    \
        float f7 = __uint_as_float((U).w & 0xFFFF0000u);            \
        if ((p) >> 28) {                                            \
            a1[0] += f0; a1[1] += f1; a1[2] += f2; a1[3] += f3;     \
            a1[4] += f4; a1[5] += f5; a1[6] += f6; a1[7] += f7;     \
        } else {                                                    \
            a0[0] += f0; a0[1] += f1; a0[2] += f2; a0[3] += f3;     \
            a0[4] += f4; a0[5] += f5; a0[6] += f6; a0[7] += f7;     \
        }                                                           \
    }

// ---------------- merged: bucket histogram + prep (x->bf16, W stacks) + zero mark/nodeCnt ----------------
__global__ __launch_bounds__(256) void prepA_kernel(const int* __restrict__ dst,
                                                    int* __restrict__ blockHist, int E, int nblk,
                                                    const float* __restrict__ x, ushort* __restrict__ xb,
                                                    const float* __restrict__ basis0, const float* __restrict__ comp0,
                                                    const float* __restrict__ root0, ushort* __restrict__ Wt0,
                                                    const float* __restrict__ basis1, const float* __restrict__ comp1,
                                                    const float* __restrict__ root1, float* __restrict__ Wst1,
                                                    int* __restrict__ mark, int* __restrict__ nodeCnt) {
    const int tid = threadIdx.x;
    if ((int)blockIdx.x < nblk) {
        __shared__ int h[NBUCK];
        for (int b = tid; b < NBUCK; b += 256) h[b] = 0;
        __syncthreads();
        const int e0 = blockIdx.x * EPB;
#pragma unroll
        for (int i = 0; i < EPB / 256; i++) {
            int e = e0 + i * 256 + tid;
            if (e < E) atomicAdd(&h[dst[e] >> BSHIFT], 1);
        }
        __syncthreads();
        const int row = blockIdx.x * NBUCK;
        for (int b = tid; b < NBUCK; b += 256) blockHist[row + b] = h[b];
        return;
    }
    const int bid = blockIdx.x - nblk;
    if (bid < NBX) {
        int i = (bid * 256 + tid) * 4;
        float4 v = *(const float4*)(x + i);
        uint2 p;
        p.x = pk2(v.x, v.y);
        p.y = pk2(v.z, v.w);
        *(uint2*)(xb + i) = p;
    } else if (bid < NBX + 192) {
        int idx = (bid - NBX) * 256 + tid;   // < 384*128
        int k = idx >> 7, o = idx & 127;
        float v;
        if (k < 256) {
            int r = k >> 7, i = k & 127;
            v = comp0[r * 2 + 0] * basis0[(size_t)(0 * 128 + i) * 128 + o]
              + comp0[r * 2 + 1] * basis0[(size_t)(1 * 128 + i) * 128 + o];
        } else {
            v = root0[(size_t)(k - 256) * 128 + o];
        }
        Wt0[(size_t)o * 384 + k] = f2bf(v);
    } else if (bid < NBX + 192 + 96) {
        int idx = (bid - NBX - 192) * 256 + tid;  // < 384*64
        int k = idx / 64, o = idx & 63;
        float v;
        if (k < 256) {
            int r = k >> 7, i = k & 127;
            v = comp1[r * 2 + 0] * basis1[(size_t)(0 * 128 + i) * 64 + o]
              + comp1[r * 2 + 1] * basis1[(size_t)(1 * 128 + i) * 64 + o];
        } else {
            v = root1[(size_t)(k - 256) * 64 + o];
        }
        Wst1[idx] = v;
    } else {
        // zero mark + nodeCnt
        const int zb = bid - NBX - 192 - 96;
        const int n = zb * 256 + tid;
        if (n < N_NODES) mark[n] = 0;
        if (zb == 0 && tid == 0) *nodeCnt = 0;
    }
}

// bscan: (1) column-scan blockHist per bucket (in place -> per-block exclusive bases),
//        (2) bucket totals -> bucketCnt, exclusive scan -> bucketBase, rowptr[N]=E.
__global__ __launch_bounds__(512) void bscan_kernel(int* __restrict__ blockHist, int nblk,
                                                    int* __restrict__ bucketCnt,
                                                    int* __restrict__ bucketBase,
                                                    int* __restrict__ rowptr, int E) {
    __shared__ int s[512];
    const int t = threadIdx.x;
    int tot = 0;
    if (t < NBUCK) {
        int run = 0;
        for (int blk = 0; blk < nblk; blk++) {
            const int idx = blk * NBUCK + t;
            const int c = blockHist[idx];
            blockHist[idx] = run;
            run += c;
        }
        bucketCnt[t] = run;
        tot = run;
    }
    s[t] = tot;
    __syncthreads();
    for (int off = 1; off < 512; off <<= 1) {
        int u = (t >= off) ? s[t - off] : 0;
        __syncthreads();
        s[t] += u;
        __syncthreads();
    }
    if (t < NBUCK) bucketBase[t] = s[t] - tot;
    if (t == 0) rowptr[N_NODES] = E;
}

// binB: binned scatter; per-block bases precomputed (no global atomics)
__global__ __launch_bounds__(256) void binB_kernel(const int* __restrict__ src,
                                                   const int* __restrict__ dst,
                                                   const int* __restrict__ etype,
                                                   const int* __restrict__ blockHist,
                                                   const int* __restrict__ bucketBase,
                                                   int* __restrict__ tmp, int E) {
    __shared__ int hBase[NBUCK];
    __shared__ int hCur[NBUCK];
    const int tid = threadIdx.x;
    const int row = blockIdx.x * NBUCK;
    for (int b = tid; b < NBUCK; b += 256) {
        hBase[b] = bucketBase[b] + blockHist[row + b];
        hCur[b] = 0;
    }
    __syncthreads();
    const int e0 = blockIdx.x * EPB;
#pragma unroll
    for (int i = 0; i < EPB / 256; i++) {
        int e = e0 + i * 256 + tid;
        if (e < E) {
            int d = dst[e];
            int b = d >> BSHIFT;
            int r = atomicAdd(&hCur[b], 1);
            tmp[hBase[b] + r] = src[e] | (etype[e] << 20) | ((d & 255) << 21);
        }
    }
}

// binC: per-bucket local counting sort by node; writes cnt, rowptr, adj
// adj entry: (src << 8) | (rel << 28)  -- pre-shifted byte offset (row = 256 B)
__global__ __launch_bounds__(256) void binC_kernel(const int* __restrict__ tmp,
                                                   const int* __restrict__ bucketBase,
                                                   const int* __restrict__ bucketCnt,
                                                   int* __restrict__ adj, int* __restrict__ cnt,
                                                   int* __restrict__ rowptr) {
    __shared__ int nc[512];
    __shared__ int nbase[256];
    __shared__ int ncur[256];
    __shared__ int sc[256];
    const int tid = threadIdx.x;
    const int b = blockIdx.x;
    const int base = bucketBase[b];
    const int m = bucketCnt[b];
    const int node0 = b << BSHIFT;
    const int nn = min(256, N_NODES - node0);

    nc[tid] = 0; nc[tid + 256] = 0; ncur[tid] = 0;
    __syncthreads();
    for (int i = tid; i < m; i += 256) {
        int v = tmp[base + i];
        atomicAdd(&nc[((v >> 21) & 255) * 2 + ((v >> 20) & 1)], 1);
    }
    __syncthreads();
    int tot = 0;
    if (tid < nn) {
        int c0 = nc[tid * 2], c1 = nc[tid * 2 + 1];
        cnt[(size_t)(node0 + tid) * 2] = c0;
        cnt[(size_t)(node0 + tid) * 2 + 1] = c1;
        tot = c0 + c1;
    }
    sc[tid] = tot;
    __syncthreads();
    for (int off = 1; off < 256; off <<= 1) {
        int u = (tid >= off) ? sc[tid - off] : 0;
        __syncthreads();
        sc[tid] += u;
        __syncthreads();
    }
    int excl = sc[tid] - tot;
    nbase[tid] = excl;
    if (tid < nn) rowptr[node0 + tid] = base + excl;
    __syncthreads();
    for (int i = tid; i < m; i += 256) {
        int v = tmp[base + i];
        int dl = (v >> 21) & 255;
        int pos = base + nbase[dl] + atomicAdd(&ncur[dl], 1);
        adj[pos] = ((v & 0xFFFFF) << 8) | (((v >> 20) & 1) << 28);
    }
}

// ---------------- mark: nodes whose x1 is needed by layer 2 ----------------
__global__ __launch_bounds__(256) void mark_kernel(const int* __restrict__ ni,
                                                   const int* __restrict__ rowptr,
                                                   const int* __restrict__ adj,
                                                   int* __restrict__ mark, int B) {
    int g = blockIdx.x * blockDim.x + threadIdx.x;
    int u = g >> 6, lane = g & 63;
    if (u >= B) return;
    int n = ni[u];
    if (lane == 0) mark[n] = 1;
    const int beg = rowptr[n], end = rowptr[n + 1];
    for (int i = beg + lane; i < end; i += 64)
        mark[(adj[i] >> 8) & 0xFFFFF] = 1;
}

// ---------------- compact: nodeList of marked nodes ----------------
__global__ __launch_bounds__(256) void compact_kernel(const int* __restrict__ mark,
                                                      int* __restrict__ nodeList,
                                                      int* __restrict__ nodeCnt) {
    __shared__ int sc[256];
    __shared__ int sbase;
    const int tid = threadIdx.x;
    const int n = blockIdx.x * 256 + tid;
    const int m = (n < N_NODES) ? mark[n] : 0;
    sc[tid] = m;
    __syncthreads();
    for (int off = 1; off < 256; off <<= 1) {
        int v = (tid >= off) ? sc[tid - off] : 0;
        __syncthreads();
        sc[tid] += v;
        __syncthreads();
    }
    if (tid == 255) sbase = atomicAdd(nodeCnt, sc[255]);
    __syncthreads();
    if (m) nodeList[sbase + sc[tid] - 1] = n;
}

// ---------------- gather0: one wave per marked node; 16 lanes x dwordx4 per edge-row ----------------
__global__ __launch_bounds__(256) void gather0_kernel(const int* __restrict__ nodeList,
                                                      const int* __restrict__ nodeCnt,
                                                      const int* __restrict__ rowptr,
                                                      const int* __restrict__ adj,
                                                      const int* __restrict__ cnt,
                                                      const ushort* __restrict__ xb,
                                                      ushort* __restrict__ A) {
    int g = blockIdx.x * blockDim.x + threadIdx.x;
    int idx = g >> 6, lane = g & 63;
    if (idx >= *nodeCnt) return;
    const int n = nodeList[idx];
    const int eg = lane >> 4;
    const int dl = lane & 15;
    const char* xbb = (const char*)xb;
    float a0[8], a1[8];
#pragma unroll
    for (int k = 0; k < 8; k++) { a0[k] = 0.f; a1[k] = 0.f; }
    const int beg = rowptr[n], end = rowptr[n + 1];
    int i = beg;
    for (; i + 8 <= end; i += 8) {      // 8 edges per iteration, 2 dwordx4 loads in flight
        const int p0 = adj[i + eg];
        const int p1 = adj[i + 4 + eg];
        const uint4 u0 = *(const uint4*)(xbb + (p0 & 0x0FFFFF00) + dl * 16);
        const uint4 u1 = *(const uint4*)(xbb + (p1 & 0x0FFFFF00) + dl * 16);
        UNPACK_ACC(p0, u0);
        UNPACK_ACC(p1, u1);
    }
    if (i + 4 <= end) {
        const int p0 = adj[i + eg];
        const uint4 u0 = *(const uint4*)(xbb + (p0 & 0x0FFFFF00) + dl * 16);
        UNPACK_ACC(p0, u0);
        i += 4;
    }
    if (i < end) {
        const int ig = i + eg;
        if (ig < end) {
            const int p0 = adj[ig];
            const uint4 u0 = *(const uint4*)(xbb + (p0 & 0x0FFFFF00) + dl * 16);
            UNPACK_ACC(p0, u0);
        }
    }
    // reduce across the 4 edge-groups
#pragma unroll
    for (int k = 0; k < 8; k++) { a0[k] += __shfl_xor(a0[k], 16); a1[k] += __shfl_xor(a1[k], 16); }
#pragma unroll
    for (int k = 0; k < 8; k++) { a0[k] += __shfl_xor(a0[k], 32); a1[k] += __shfl_xor(a1[k], 32); }

    const int c0 = cnt[n * 2], c1 = cnt[n * 2 + 1];
    const float s0 = c0 > 0 ? 1.f / (float)c0 : 0.f;
    const float s1 = c1 > 0 ? 1.f / (float)c1 : 0.f;
    const float sc = (eg & 1) ? s1 : s0;
    float r[8];
#pragma unroll
    for (int k = 0; k < 8; k++) r[k] = ((eg & 1) ? a1[k] : a0[k]) * sc;
    if (eg < 2) {   // lanes 0-15 write rel0 row, 16-31 write rel1 row
        uint4 o;
        o.x = pk2(r[0], r[1]); o.y = pk2(r[2], r[3]);
        o.z = pk2(r[4], r[5]); o.w = pk2(r[6], r[7]);
        *(uint4*)(A + (size_t)n * 256 + eg * 128 + dl * 8) = o;
    }
}

// ---------------- gemm0 (MFMA bf16): x1[nodeList rows] = relu([A | x] @ W + bias) ----------------
#define BM 128
#define BK 64
__global__ __launch_bounds__(256) void gemm0_kernel(const ushort* __restrict__ A,    // [N][256]
                                                    const ushort* __restrict__ xb,   // [N][128]
                                                    const int* __restrict__ nodeList,
                                                    const int* __restrict__ nodeCnt,
                                                    const ushort* __restrict__ Wt,   // [128][384]
                                                    const float* __restrict__ bias,
                                                    ushort* __restrict__ x1) {
    const int NC = *nodeCnt;
    const int row0 = blockIdx.x * BM;
    if (row0 >= NC) return;
    __shared__ ushort As[BM][BK + 8];
    __shared__ ushort Ws[128][BK + 8];
    const int tid = threadIdx.x;
    const int lane = tid & 63;
    const int w = tid >> 6;

    f32x4 acc[2][8];
#pragma unroll
    for (int t = 0; t < 2; t++)
#pragma unroll
        for (int c = 0; c < 8; c++) acc[t][c] = (f32x4)0.f;

    for (int kc = 0; kc < 384; kc += BK) {
        __syncthreads();
#pragma unroll
        for (int q = 0; q < 4; q++) {
            const int seg = q * 256 + tid;       // 0..1023
            const int row = seg >> 3;            // 0..127
            const int sk = (seg & 7) * 8;
            const int gr = nodeList[min(row0 + row, NC - 1)];
            uint4 val;
            if (kc < 256) val = *(const uint4*)&A[(size_t)gr * 256 + kc + sk];
            else          val = *(const uint4*)&xb[(size_t)gr * 128 + (kc - 256) + sk];
            *(uint4*)&As[row][sk] = val;
            *(uint4*)&Ws[row][sk] = *(const uint4*)&Wt[(size_t)row * 384 + kc + sk];
        }
        __syncthreads();
#pragma unroll
        for (int k2 = 0; k2 < 2; k2++) {
            const int kk = k2 * 32 + (lane >> 4) * 8;
            const bf16x8 af0 = *(const bf16x8*)&As[w * 32 + (lane & 15)][kk];
            const bf16x8 af1 = *(const bf16x8*)&As[w * 32 + 16 + (lane & 15)][kk];
            bf16x8 bf[8];
#pragma unroll
            for (int c = 0; c < 8; c++) bf[c] = *(const bf16x8*)&Ws[c * 16 + (lane & 15)][kk];
#pragma unroll
            for (int c = 0; c < 8; c++) {
                acc[0][c] = __builtin_amdgcn_mfma_f32_16x16x32_bf16(af0, bf[c], acc[0][c], 0, 0, 0);
                acc[1][c] = __builtin_amdgcn_mfma_f32_16x16x32_bf16(af1, bf[c], acc[1][c], 0, 0, 0);
            }
        }
    }

    // D layout: col = lane&15, row = (lane>>4)*4 + j
#pragma unroll
    for (int c = 0; c < 8; c++) {
        const int col = c * 16 + (lane & 15);
        const float b = bias[col];
#pragma unroll
        for (int t = 0; t < 2; t++) {
#pragma unroll
            for (int j = 0; j < 4; j++) {
                const int rIdx = row0 + w * 32 + t * 16 + (lane >> 4) * 4 + j;
                if (rIdx < NC) x1[(size_t)nodeList[rIdx] * 128 + col] = f2bf(fmaxf(acc[t][c][j] + b, 0.f));
            }
        }
    }
}

// ---------------- fused tail: gather1 + gemm2 + MLP head ----------------
__global__ __launch_bounds__(256) void tail_kernel(const int* __restrict__ ni,
                                                   const int* __restrict__ rowptr,
                                                   const int* __restrict__ adj,
                                                   const int* __restrict__ cnt,
                                                   const ushort* __restrict__ x1,
                                                   const float* __restrict__ Wst,   // [384][64]
                                                   const float* __restrict__ bias,
                                                   const float* __restrict__ W1, const float* __restrict__ b1,
                                                   const float* __restrict__ g1, const float* __restrict__ be1,
                                                   const float* __restrict__ W2, const float* __restrict__ b2,
                                                   const float* __restrict__ g2, const float* __restrict__ be2,
                                                   const float* __restrict__ W3, const float* __restrict__ b3,
                                                   float* __restrict__ outExpert, float* __restrict__ outProb,
                                                   int B) {
    __shared__ float As[16][384];
    __shared__ float x2s[16][64];
    const int tid = threadIdx.x;
    const int lane = tid & 63;
    const int w = tid >> 6;
    const int row0 = blockIdx.x * 16;
    const int eg = lane >> 4;
    const int dl = lane & 15;
    const char* x1b = (const char*)x1;

    // ---- phase 1: gather A rows [agg0 | agg1 | x1[n]] into LDS ----
    for (int j = 0; j < 4; j++) {
        const int r = w + j * 4;
        const int u = row0 + r;
        if (u < B) {
            const int n = ni[u];
            float a0[8], a1[8];
#pragma unroll
            for (int k = 0; k < 8; k++) { a0[k] = 0.f; a1[k] = 0.f; }
            const int beg = rowptr[n], end = rowptr[n + 1];
            int i = beg;
            for (; i + 8 <= end; i += 8) {
                const int p0 = adj[i + eg];
                const int p1 = adj[i + 4 + eg];
                const uint4 u0 = *(const uint4*)(x1b + (p0 & 0x0FFFFF00) + dl * 16);
                const uint4 u1 = *(const uint4*)(x1b + (p1 & 0x0FFFFF00) + dl * 16);
                UNPACK_ACC(p0, u0);
                UNPACK_ACC(p1, u1);
            }
            if (i + 4 <= end) {
                const int p0 = adj[i + eg];
                const uint4 u0 = *(const uint4*)(x1b + (p0 & 0x0FFFFF00) + dl * 16);
                UNPACK_ACC(p0, u0);
                i += 4;
            }
            if (i < end) {
                const int ig = i + eg;
                if (ig < end) {
                    const int p0 = adj[ig];
                    const uint4 u0 = *(const uint4*)(x1b + (p0 & 0x0FFFFF00) + dl * 16);
                    UNPACK_ACC(p0, u0);
                }
            }
#pragma unroll
            for (int k = 0; k < 8; k++) { a0[k] += __shfl_xor(a0[k], 16); a1[k] += __shfl_xor(a1[k], 16); }
#pragma unroll
            for (int k = 0; k < 8; k++) { a0[k] += __shfl_xor(a0[k], 32); a1[k] += __shfl_xor(a1[k], 32); }
            const int c0 = cnt[n * 2], c1 = cnt[n * 2 + 1];
            const float s0 = c0 > 0 ? 1.f / (float)c0 : 0.f;
            const float s1 = c1 > 0 ? 1.f / (float)c1 : 0.f;
            if (eg == 0) {
#pragma unroll
                for (int k = 0; k < 8; k++) As[r][dl * 8 + k] = a0[k] * s0;
            } else if (eg == 1) {
#pragma unroll
                for (int k = 0; k < 8; k++) As[r][128 + dl * 8 + k] = a1[k] * s1;
            } else if (eg == 2) {
                const uint4 ux = *(const uint4*)(x1 + (size_t)n * 128 + dl * 8);
                As[r][256 + dl * 8 + 0] = __uint_as_float(ux.x << 16);
                As[r][256 + dl * 8 + 1] = __uint_as_float(ux.x & 0xFFFF0000u);
                As[r][256 + dl * 8 + 2] = __uint_as_float(ux.y << 16);
                As[r][256 + dl * 8 + 3] = __uint_as_float(ux.y & 0xFFFF0000u);
                As[r][256 + dl * 8 + 4] = __uint_as_float(ux.z << 16);
                As[r][256 + dl * 8 + 5] = __uint_as_float(ux.z & 0xFFFF0000u);
                As[r][256 + dl * 8 + 6] = __uint_as_float(ux.w << 16);
                As[r][256 + dl * 8 + 7] = __uint_as_float(ux.w & 0xFFFF0000u);
            }
        }
    }
    __syncthreads();

    // ---- phase 2: gemm 16x384 @ 384x64 ----
    {
        const int o = tid & 63;
        const int q = tid >> 6;
        float acc[4] = {0.f, 0.f, 0.f, 0.f};
        for (int k = 0; k < 384; k += 4) {
            const float w0 = Wst[(k + 0) * 64 + o];
            const float w1_ = Wst[(k + 1) * 64 + o];
            const float w2_ = Wst[(k + 2) * 64 + o];
            const float w3_ = Wst[(k + 3) * 64 + o];
#pragma unroll
            for (int rr = 0; rr < 4; rr++) {
                const float4 a = *(const float4*)&As[q * 4 + rr][k];
                acc[rr] = fmaf(a.x, w0, acc[rr]);
                acc[rr] = fmaf(a.y, w1_, acc[rr]);
                acc[rr] = fmaf(a.z, w2_, acc[rr]);
                acc[rr] = fmaf(a.w, w3_, acc[rr]);
            }
        }
        const float bb = bias[o];
#pragma unroll
        for (int rr = 0; rr < 4; rr++) x2s[q * 4 + rr][o] = acc[rr] + bb;
    }
    __syncthreads();

    // ---- phase 3: MLP head, wave w handles rows w*4..w*4+3 ----
    for (int rr = 0; rr < 4; rr++) {
        const int r = w * 4 + rr;
        const int i = row0 + r;
        if (i >= B) continue;
        const int t = lane;
        const int tt = lane & 31;
        float e = x2s[r][t];
        outExpert[(size_t)i * 64 + t] = e;

        float y = b1[t];
#pragma unroll
        for (int k = 0; k < 64; k++) y = fmaf(__shfl(e, k), W1[k * 64 + t], y);
        float s = y;
        for (int off = 32; off; off >>= 1) s += __shfl_xor(s, off);
        float m = s * (1.f / 64.f);
        float d = y - m;
        float vs = d * d;
        for (int off = 32; off; off >>= 1) vs += __shfl_xor(vs, off);
        float h1 = fmaxf(fmaf(g1[t] * d, rsqrtf(vs * (1.f / 64.f) + 1e-5f), be1[t]), 0.f);

        float y2 = b2[tt];
#pragma unroll
        for (int k = 0; k < 64; k++) y2 = fmaf(__shfl(h1, k), W2[k * 32 + tt], y2);
        float s2 = y2;
        for (int off = 16; off; off >>= 1) s2 += __shfl_xor(s2, off);
        float m2 = s2 * (1.f / 32.f);
        float d2 = y2 - m2;
        float v2 = d2 * d2;
        for (int off = 16; off; off >>= 1) v2 += __shfl_xor(v2, off);
        float h2 = fmaxf(fmaf(g2[tt] * d2, rsqrtf(v2 * (1.f / 32.f) + 1e-5f), be2[tt]), 0.f);

        float p = h2 * W3[tt];
        for (int off = 16; off; off >>= 1) p += __shfl_xor(p, off);
        if (t == 0) outProb[i] = 1.f / (1.f + expf(-(p + b3[0])));
    }
}

extern "C" void kernel_launch(void* const* d_in, const int* in_sizes, int n_in,
                              void* d_out, int out_size, void* d_ws, size_t ws_size,
                              hipStream_t stream) {
    const int*   node_indices = (const int*)d_in[0];
    const int*   edge_index   = (const int*)d_in[1];
    const int*   edge_type    = (const int*)d_in[2];
    const float* x_feat       = (const float*)d_in[3];
    const float* basis0       = (const float*)d_in[4];
    const float* comp0        = (const float*)d_in[5];
    const float* root0        = (const float*)d_in[6];
    const float* bias0        = (const float*)d_in[7];
    const float* basis1       = (const float*)d_in[8];
    const float* comp1        = (const float*)d_in[9];
    const float* root1        = (const float*)d_in[10];
    const float* bias1        = (const float*)d_in[11];
    const float* W1 = (const float*)d_in[12];
    const float* b1 = (const float*)d_in[13];
    const float* g1 = (const float*)d_in[14];
    const float* be1 = (const float*)d_in[15];
    const float* W2 = (const float*)d_in[16];
    const float* b2 = (const float*)d_in[17];
    const float* g2 = (const float*)d_in[18];
    const float* be2 = (const float*)d_in[19];
    const float* W3 = (const float*)d_in[20];
    const float* b3 = (const float*)d_in[21];

    const int B = in_sizes[0];
    const int E = in_sizes[1] / 2;
    const int* src = edge_index;
    const int* dst = edge_index + E;
    const int nblk = (E + EPB - 1) / EPB;   // 782 for E=1.6M

    // ---- workspace carve-out (256B aligned) ----
    size_t off = 0;
    auto alloc = [&](size_t sz) { size_t o = off; off = (off + sz + 255) & ~(size_t)255; return o; };
    char* ws = (char*)d_ws;
    ushort* xb    = (ushort*)(ws + alloc((size_t)N_NODES * 128 * 2));
    ushort* Amat  = (ushort*)(ws + alloc((size_t)N_NODES * 256 * 2));
    ushort* x1b   = (ushort*)(ws + alloc((size_t)N_NODES * 128 * 2));
    int*   cnt    = (int*)  (ws + alloc((size_t)N_NODES * 2 * 4));
    int*   rowptr = (int*)  (ws + alloc((size_t)(N_NODES + 1) * 4));
    int*   adj    = (int*)  (ws + alloc((size_t)E * 4));
    int*   tmp    = (int*)  (ws + alloc((size_t)E * 4));
    int*   blockHist  = (int*)(ws + alloc((size_t)nblk * NBUCK * 4));
    int*   bucketCnt  = (int*)(ws + alloc((size_t)NBUCK * 4));
    int*   bucketBase = (int*)(ws + alloc((size_t)NBUCK * 4));
    int*   mark     = (int*)(ws + alloc((size_t)N_NODES * 4));
    int*   nodeList = (int*)(ws + alloc((size_t)N_NODES * 4));
    int*   nodeCnt  = (int*)(ws + alloc(256));
    ushort* Wt0b  = (ushort*)(ws + alloc((size_t)128 * 384 * 2));
    float* Wst1   = (float*)(ws + alloc((size_t)384 * 64 * 4));

    float* outExpert = (float*)d_out;
    float* outProb   = (float*)d_out + (size_t)B * 64;

    // ---- merged hist + prep + zero (no memsets) ----
    prepA_kernel<<<nblk + NBX + 192 + 96 + NZB, 256, 0, stream>>>(dst, blockHist, E, nblk,
                                                                  x_feat, xb, basis0, comp0, root0, Wt0b,
                                                                  basis1, comp1, root1, Wst1,
                                                                  mark, nodeCnt);

    // ---- CSR build (atomic-free bases) ----
    bscan_kernel<<<1, 512, 0, stream>>>(blockHist, nblk, bucketCnt, bucketBase, rowptr, E);
    binB_kernel<<<nblk, 256, 0, stream>>>(src, dst, edge_type, blockHist, bucketBase, tmp, E);
    binC_kernel<<<NBUCK, 256, 0, stream>>>(tmp, bucketBase, bucketCnt, adj, cnt, rowptr);

    // ---- mark + compact needed nodes ----
    mark_kernel<<<((size_t)B * 64 + 255) / 256, 256, 0, stream>>>(node_indices, rowptr, adj, mark, B);
    compact_kernel<<<NBUCK, 256, 0, stream>>>(mark, nodeList, nodeCnt);

    // ---- layer 0 (marked nodes only) ----
    gather0_kernel<<<(N_NODES * 64 + 255) / 256, 256, 0, stream>>>(nodeList, nodeCnt, rowptr, adj, cnt, xb, Amat);
    gemm0_kernel<<<(N_NODES + BM - 1) / BM, 256, 0, stream>>>(Amat, xb, nodeList, nodeCnt, Wt0b, bias0, x1b);

    // ---- layer 1 + head (fused) ----
    tail_kernel<<<(B + 15) / 16, 256, 0, stream>>>(node_indices, rowptr, adj, cnt, x1b,
                                                   Wst1, bias1,
                                                   W1, b1, g1, be1, W2, b2, g2, be2, W3, b3,
                                                   outExpert, outProb, B);
}

// Round 15
// 167.900 us; speedup vs baseline: 2.0287x; 2.0287x over previous
//
#include <hip/hip_runtime.h>
#include <math.h>

#define N_NODES 100000
#define NREL 2
#define BATCH_MAX 4096
#define BSHIFT 8
#define NBUCK ((N_NODES + 255) >> 8)   // 391
#define EPB 2048                       // edges per block in hist/binB
#define NBX 12500                      // tobf16 blocks: N*128/4/256
#define NZB 391                        // zero-mark blocks

typedef __attribute__((ext_vector_type(8))) short bf16x8;
typedef __attribute__((ext_vector_type(4))) float f32x4;

__device__ inline ushort f2bf(float f) {
    unsigned u = __float_as_uint(f);
    u += 0x7FFF + ((u >> 16) & 1);
    return (ushort)(u >> 16);
}
__device__ inline unsigned pk2(float lo, float hi) {
    return ((unsigned)f2bf(lo)) | (((unsigned)f2bf(hi)) << 16);
}

// unpack uint4 (8 bf16) and accumulate into a0[8]/a1[8] by relation bit (p>>28)
#define UNPACK_ACC(p, U)                                            \
    {                                                               \
        float f0 = __uint_as_float((U).x << 16);                    \
        float f1 = __uint_as_float((U).x & 0xFFFF0000u);            \
        float f2 = __uint_as_float((U).y << 16);                    \
        float f3 = __uint_as_float((U).y & 0xFFFF0000u);            \
        float f4 = __uint_as_float((U).z << 16);                    \
        float f5 = __uint_as_float((U).z & 0xFFFF0000u);            \
        float f6 = __uint_as_float((U).w << 16);                    \
        float f7 = __uint_as_float((U).w & 0xFFFF0000u);            \
        if ((p) >> 28) {                                            \
            a1[0] += f0; a1[1] += f1; a1[2] += f2; a1[3] += f3;     \
            a1[4] += f4; a1[5] += f5; a1[6] += f6; a1[7] += f7;     \
        } else {                                                    \
            a0[0] += f0; a0[1] += f1; a0[2] += f2; a0[3] += f3;     \
            a0[4] += f4; a0[5] += f5; a0[6] += f6; a0[7] += f7;     \
        }                                                           \
    }

// ---------------- merged: bucket histogram + prep (x->bf16, W stacks) + zero mark/nodeCnt ----------------
__global__ __launch_bounds__(256) void prepA_kernel(const int* __restrict__ dst,
                                                    int* __restrict__ blockHist, int E, int nblk,
                                                    const float* __restrict__ x, ushort* __restrict__ xb,
                                                    const float* __restrict__ basis0, const float* __restrict__ comp0,
                                                    const float* __restrict__ root0, ushort* __restrict__ Wt0,
                                                    const float* __restrict__ basis1, const float* __restrict__ comp1,
                                                    const float* __restrict__ root1, float* __restrict__ Wst1,
                                                    int* __restrict__ mark, int* __restrict__ nodeCnt) {
    const int tid = threadIdx.x;
    if ((int)blockIdx.x < nblk) {
        __shared__ int h[NBUCK];
        for (int b = tid; b < NBUCK; b += 256) h[b] = 0;
        __syncthreads();
        const int e0 = blockIdx.x * EPB;
#pragma unroll
        for (int i = 0; i < EPB / 256; i++) {
            int e = e0 + i * 256 + tid;
            if (e < E) atomicAdd(&h[dst[e] >> BSHIFT], 1);
        }
        __syncthreads();
        const int row = blockIdx.x * NBUCK;
        for (int b = tid; b < NBUCK; b += 256) blockHist[row + b] = h[b];
        return;
    }
    const int bid = blockIdx.x - nblk;
    if (bid < NBX) {
        int i = (bid * 256 + tid) * 4;
        float4 v = *(const float4*)(x + i);
        uint2 p;
        p.x = pk2(v.x, v.y);
        p.y = pk2(v.z, v.w);
        *(uint2*)(xb + i) = p;
    } else if (bid < NBX + 192) {
        int idx = (bid - NBX) * 256 + tid;   // < 384*128
        int k = idx >> 7, o = idx & 127;
        float v;
        if (k < 256) {
            int r = k >> 7, i = k & 127;
            v = comp0[r * 2 + 0] * basis0[(size_t)(0 * 128 + i) * 128 + o]
              + comp0[r * 2 + 1] * basis0[(size_t)(1 * 128 + i) * 128 + o];
        } else {
            v = root0[(size_t)(k - 256) * 128 + o];
        }
        Wt0[(size_t)o * 384 + k] = f2bf(v);
    } else if (bid < NBX + 192 + 96) {
        int idx = (bid - NBX - 192) * 256 + tid;  // < 384*64
        int k = idx / 64, o = idx & 63;
        float v;
        if (k < 256) {
            int r = k >> 7, i = k & 127;
            v = comp1[r * 2 + 0] * basis1[(size_t)(0 * 128 + i) * 64 + o]
              + comp1[r * 2 + 1] * basis1[(size_t)(1 * 128 + i) * 64 + o];
        } else {
            v = root1[(size_t)(k - 256) * 64 + o];
        }
        Wst1[idx] = v;
    } else {
        // zero mark + nodeCnt
        const int zb = bid - NBX - 192 - 96;
        const int n = zb * 256 + tid;
        if (n < N_NODES) mark[n] = 0;
        if (zb == 0 && tid == 0) *nodeCnt = 0;
    }
}

// cscan: one block per bucket — exclusive scan of that bucket's per-block counts (in place),
//        total -> bucketCnt[b]. Chunked Hillis-Steele over nblk entries.
__global__ __launch_bounds__(256) void cscan_kernel(int* __restrict__ blockHist, int nblk,
                                                    int* __restrict__ bucketCnt) {
    __shared__ int s[256];
    __shared__ int carry;
    const int tid = threadIdx.x;
    const int b = blockIdx.x;
    if (tid == 0) carry = 0;
    __syncthreads();
    for (int c0 = 0; c0 < nblk; c0 += 256) {
        const int blk = c0 + tid;
        const int idx = blk * NBUCK + b;
        int v = (blk < nblk) ? blockHist[idx] : 0;
        s[tid] = v;
        __syncthreads();
        for (int off = 1; off < 256; off <<= 1) {
            int u = (tid >= off) ? s[tid - off] : 0;
            __syncthreads();
            s[tid] += u;
            __syncthreads();
        }
        const int incl = s[tid];
        const int excl = incl - v;
        const int carryLocal = carry;
        if (blk < nblk) blockHist[idx] = carryLocal + excl;
        __syncthreads();
        if (tid == 255) carry = carryLocal + incl;
        __syncthreads();
    }
    if (tid == 0) bucketCnt[b] = carry;
}

// bscan2: exclusive scan of bucket totals -> bucketBase; rowptr[N]=E
__global__ __launch_bounds__(512) void bscan2_kernel(const int* __restrict__ bucketCnt,
                                                     int* __restrict__ bucketBase,
                                                     int* __restrict__ rowptr, int E) {
    __shared__ int s[512];
    const int t = threadIdx.x;
    int v = (t < NBUCK) ? bucketCnt[t] : 0;
    s[t] = v;
    __syncthreads();
    for (int off = 1; off < 512; off <<= 1) {
        int u = (t >= off) ? s[t - off] : 0;
        __syncthreads();
        s[t] += u;
        __syncthreads();
    }
    if (t < NBUCK) bucketBase[t] = s[t] - v;
    if (t == 0) rowptr[N_NODES] = E;
}

// binB: binned scatter; per-block bases precomputed (no global atomics)
__global__ __launch_bounds__(256) void binB_kernel(const int* __restrict__ src,
                                                   const int* __restrict__ dst,
                                                   const int* __restrict__ etype,
                                                   const int* __restrict__ blockHist,
                                                   const int* __restrict__ bucketBase,
                                                   int* __restrict__ tmp, int E) {
    __shared__ int hBase[NBUCK];
    __shared__ int hCur[NBUCK];
    const int tid = threadIdx.x;
    const int row = blockIdx.x * NBUCK;
    for (int b = tid; b < NBUCK; b += 256) {
        hBase[b] = bucketBase[b] + blockHist[row + b];
        hCur[b] = 0;
    }
    __syncthreads();
    const int e0 = blockIdx.x * EPB;
#pragma unroll
    for (int i = 0; i < EPB / 256; i++) {
        int e = e0 + i * 256 + tid;
        if (e < E) {
            int d = dst[e];
            int b = d >> BSHIFT;
            int r = atomicAdd(&hCur[b], 1);
            tmp[hBase[b] + r] = src[e] | (etype[e] << 20) | ((d & 255) << 21);
        }
    }
}

// binC: per-bucket local counting sort by node; writes cnt, rowptr, adj
// adj entry: (src << 8) | (rel << 28)  -- pre-shifted byte offset (row = 256 B)
__global__ __launch_bounds__(256) void binC_kernel(const int* __restrict__ tmp,
                                                   const int* __restrict__ bucketBase,
                                                   const int* __restrict__ bucketCnt,
                                                   int* __restrict__ adj, int* __restrict__ cnt,
                                                   int* __restrict__ rowptr) {
    __shared__ int nc[512];
    __shared__ int nbase[256];
    __shared__ int ncur[256];
    __shared__ int sc[256];
    const int tid = threadIdx.x;
    const int b = blockIdx.x;
    const int base = bucketBase[b];
    const int m = bucketCnt[b];
    const int node0 = b << BSHIFT;
    const int nn = min(256, N_NODES - node0);

    nc[tid] = 0; nc[tid + 256] = 0; ncur[tid] = 0;
    __syncthreads();
    for (int i = tid; i < m; i += 256) {
        int v = tmp[base + i];
        atomicAdd(&nc[((v >> 21) & 255) * 2 + ((v >> 20) & 1)], 1);
    }
    __syncthreads();
    int tot = 0;
    if (tid < nn) {
        int c0 = nc[tid * 2], c1 = nc[tid * 2 + 1];
        cnt[(size_t)(node0 + tid) * 2] = c0;
        cnt[(size_t)(node0 + tid) * 2 + 1] = c1;
        tot = c0 + c1;
    }
    sc[tid] = tot;
    __syncthreads();
    for (int off = 1; off < 256; off <<= 1) {
        int u = (tid >= off) ? sc[tid - off] : 0;
        __syncthreads();
        sc[tid] += u;
        __syncthreads();
    }
    int excl = sc[tid] - tot;
    nbase[tid] = excl;
    if (tid < nn) rowptr[node0 + tid] = base + excl;
    __syncthreads();
    for (int i = tid; i < m; i += 256) {
        int v = tmp[base + i];
        int dl = (v >> 21) & 255;
        int pos = base + nbase[dl] + atomicAdd(&ncur[dl], 1);
        adj[pos] = ((v & 0xFFFFF) << 8) | (((v >> 20) & 1) << 28);
    }
}

// ---------------- mark: nodes whose x1 is needed by layer 2 ----------------
__global__ __launch_bounds__(256) void mark_kernel(const int* __restrict__ ni,
                                                   const int* __restrict__ rowptr,
                                                   const int* __restrict__ adj,
                                                   int* __restrict__ mark, int B) {
    int g = blockIdx.x * blockDim.x + threadIdx.x;
    int u = g >> 6, lane = g & 63;
    if (u >= B) return;
    int n = ni[u];
    if (lane == 0) mark[n] = 1;
    const int beg = rowptr[n], end = rowptr[n + 1];
    for (int i = beg + lane; i < end; i += 64)
        mark[(adj[i] >> 8) & 0xFFFFF] = 1;
}

// ---------------- compact: nodeList of marked nodes ----------------
__global__ __launch_bounds__(256) void compact_kernel(const int* __restrict__ mark,
                                                      int* __restrict__ nodeList,
                                                      int* __restrict__ nodeCnt) {
    __shared__ int sc[256];
    __shared__ int sbase;
    const int tid = threadIdx.x;
    const int n = blockIdx.x * 256 + tid;
    const int m = (n < N_NODES) ? mark[n] : 0;
    sc[tid] = m;
    __syncthreads();
    for (int off = 1; off < 256; off <<= 1) {
        int v = (tid >= off) ? sc[tid - off] : 0;
        __syncthreads();
        sc[tid] += v;
        __syncthreads();
    }
    if (tid == 255) sbase = atomicAdd(nodeCnt, sc[255]);
    __syncthreads();
    if (m) nodeList[sbase + sc[tid] - 1] = n;
}

// ---------------- gather0: one wave per marked node; 16 lanes x dwordx4 per edge-row ----------------
__global__ __launch_bounds__(256) void gather0_kernel(const int* __restrict__ nodeList,
                                                      const int* __restrict__ nodeCnt,
                                                      const int* __restrict__ rowptr,
                                                      const int* __restrict__ adj,
                                                      const int* __restrict__ cnt,
                                                      const ushort* __restrict__ xb,
                                                      ushort* __restrict__ A) {
    int g = blockIdx.x * blockDim.x + threadIdx.x;
    int idx = g >> 6, lane = g & 63;
    if (idx >= *nodeCnt) return;
    const int n = nodeList[idx];
    const int eg = lane >> 4;
    const int dl = lane & 15;
    const char* xbb = (const char*)xb;
    float a0[8], a1[8];
#pragma unroll
    for (int k = 0; k < 8; k++) { a0[k] = 0.f; a1[k] = 0.f; }
    const int beg = rowptr[n], end = rowptr[n + 1];
    int i = beg;
    for (; i + 8 <= end; i += 8) {      // 8 edges per iteration, 2 dwordx4 loads in flight
        const int p0 = adj[i + eg];
        const int p1 = adj[i + 4 + eg];
        const uint4 u0 = *(const uint4*)(xbb + (p0 & 0x0FFFFF00) + dl * 16);
        const uint4 u1 = *(const uint4*)(xbb + (p1 & 0x0FFFFF00) + dl * 16);
        UNPACK_ACC(p0, u0);
        UNPACK_ACC(p1, u1);
    }
    if (i + 4 <= end) {
        const int p0 = adj[i + eg];
        const uint4 u0 = *(const uint4*)(xbb + (p0 & 0x0FFFFF00) + dl * 16);
        UNPACK_ACC(p0, u0);
        i += 4;
    }
    if (i < end) {
        const int ig = i + eg;
        if (ig < end) {
            const int p0 = adj[ig];
            const uint4 u0 = *(const uint4*)(xbb + (p0 & 0x0FFFFF00) + dl * 16);
            UNPACK_ACC(p0, u0);
        }
    }
    // reduce across the 4 edge-groups
#pragma unroll
    for (int k = 0; k < 8; k++) { a0[k] += __shfl_xor(a0[k], 16); a1[k] += __shfl_xor(a1[k], 16); }
#pragma unroll
    for (int k = 0; k < 8; k++) { a0[k] += __shfl_xor(a0[k], 32); a1[k] += __shfl_xor(a1[k], 32); }

    const int c0 = cnt[n * 2], c1 = cnt[n * 2 + 1];
    const float s0 = c0 > 0 ? 1.f / (float)c0 : 0.f;
    const float s1 = c1 > 0 ? 1.f / (float)c1 : 0.f;
    const float sc = (eg & 1) ? s1 : s0;
    float r[8];
#pragma unroll
    for (int k = 0; k < 8; k++) r[k] = ((eg & 1) ? a1[k] : a0[k]) * sc;
    if (eg < 2) {   // lanes 0-15 write rel0 row, 16-31 write rel1 row
        uint4 o;
        o.x = pk2(r[0], r[1]); o.y = pk2(r[2], r[3]);
        o.z = pk2(r[4], r[5]); o.w = pk2(r[6], r[7]);
        *(uint4*)(A + (size_t)n * 256 + eg * 128 + dl * 8) = o;
    }
}

// ---------------- gemm0 (MFMA bf16): x1[nodeList rows] = relu([A | x] @ W + bias) ----------------
#define BM 128
#define BK 64
__global__ __launch_bounds__(256) void gemm0_kernel(const ushort* __restrict__ A,    // [N][256]
                                                    const ushort* __restrict__ xb,   // [N][128]
                                                    const int* __restrict__ nodeList,
                                                    const int* __restrict__ nodeCnt,
                                                    const ushort* __restrict__ Wt,   // [128][384]
                                                    const float* __restrict__ bias,
                                                    ushort* __restrict__ x1) {
    const int NC = *nodeCnt;
    const int row0 = blockIdx.x * BM;
    if (row0 >= NC) return;
    __shared__ ushort As[BM][BK + 8];
    __shared__ ushort Ws[128][BK + 8];
    const int tid = threadIdx.x;
    const int lane = tid & 63;
    const int w = tid >> 6;

    f32x4 acc[2][8];
#pragma unroll
    for (int t = 0; t < 2; t++)
#pragma unroll
        for (int c = 0; c < 8; c++) acc[t][c] = (f32x4)0.f;

    for (int kc = 0; kc < 384; kc += BK) {
        __syncthreads();
#pragma unroll
        for (int q = 0; q < 4; q++) {
            const int seg = q * 256 + tid;       // 0..1023
            const int row = seg >> 3;            // 0..127
            const int sk = (seg & 7) * 8;
            const int gr = nodeList[min(row0 + row, NC - 1)];
            uint4 val;
            if (kc < 256) val = *(const uint4*)&A[(size_t)gr * 256 + kc + sk];
            else          val = *(const uint4*)&xb[(size_t)gr * 128 + (kc - 256) + sk];
            *(uint4*)&As[row][sk] = val;
            *(uint4*)&Ws[row][sk] = *(const uint4*)&Wt[(size_t)row * 384 + kc + sk];
        }
        __syncthreads();
#pragma unroll
        for (int k2 = 0; k2 < 2; k2++) {
            const int kk = k2 * 32 + (lane >> 4) * 8;
            const bf16x8 af0 = *(const bf16x8*)&As[w * 32 + (lane & 15)][kk];
            const bf16x8 af1 = *(const bf16x8*)&As[w * 32 + 16 + (lane & 15)][kk];
            bf16x8 bf[8];
#pragma unroll
            for (int c = 0; c < 8; c++) bf[c] = *(const bf16x8*)&Ws[c * 16 + (lane & 15)][kk];
#pragma unroll
            for (int c = 0; c < 8; c++) {
                acc[0][c] = __builtin_amdgcn_mfma_f32_16x16x32_bf16(af0, bf[c], acc[0][c], 0, 0, 0);
                acc[1][c] = __builtin_amdgcn_mfma_f32_16x16x32_bf16(af1, bf[c], acc[1][c], 0, 0, 0);
            }
        }
    }

    // D layout: col = lane&15, row = (lane>>4)*4 + j
#pragma unroll
    for (int c = 0; c < 8; c++) {
        const int col = c * 16 + (lane & 15);
        const float b = bias[col];
#pragma unroll
        for (int t = 0; t < 2; t++) {
#pragma unroll
            for (int j = 0; j < 4; j++) {
                const int rIdx = row0 + w * 32 + t * 16 + (lane >> 4) * 4 + j;
                if (rIdx < NC) x1[(size_t)nodeList[rIdx] * 128 + col] = f2bf(fmaxf(acc[t][c][j] + b, 0.f));
            }
        }
    }
}

// ---------------- fused tail: gather1 + gemm2 + MLP head ----------------
__global__ __launch_bounds__(256) void tail_kernel(const int* __restrict__ ni,
                                                   const int* __restrict__ rowptr,
                                                   const int* __restrict__ adj,
                                                   const int* __restrict__ cnt,
                                                   const ushort* __restrict__ x1,
                                                   const float* __restrict__ Wst,   // [384][64]
                                                   const float* __restrict__ bias,
                                                   const float* __restrict__ W1, const float* __restrict__ b1,
                                                   const float* __restrict__ g1, const float* __restrict__ be1,
                                                   const float* __restrict__ W2, const float* __restrict__ b2,
                                                   const float* __restrict__ g2, const float* __restrict__ be2,
                                                   const float* __restrict__ W3, const float* __restrict__ b3,
                                                   float* __restrict__ outExpert, float* __restrict__ outProb,
                                                   int B) {
    __shared__ float As[16][384];
    __shared__ float x2s[16][64];
    const int tid = threadIdx.x;
    const int lane = tid & 63;
    const int w = tid >> 6;
    const int row0 = blockIdx.x * 16;
    const int eg = lane >> 4;
    const int dl = lane & 15;
    const char* x1b = (const char*)x1;

    // ---- phase 1: gather A rows [agg0 | agg1 | x1[n]] into LDS ----
    for (int j = 0; j < 4; j++) {
        const int r = w + j * 4;
        const int u = row0 + r;
        if (u < B) {
            const int n = ni[u];
            float a0[8], a1[8];
#pragma unroll
            for (int k = 0; k < 8; k++) { a0[k] = 0.f; a1[k] = 0.f; }
            const int beg = rowptr[n], end = rowptr[n + 1];
            int i = beg;
            for (; i + 8 <= end; i += 8) {
                const int p0 = adj[i + eg];
                const int p1 = adj[i + 4 + eg];
                const uint4 u0 = *(const uint4*)(x1b + (p0 & 0x0FFFFF00) + dl * 16);
                const uint4 u1 = *(const uint4*)(x1b + (p1 & 0x0FFFFF00) + dl * 16);
                UNPACK_ACC(p0, u0);
                UNPACK_ACC(p1, u1);
            }
            if (i + 4 <= end) {
                const int p0 = adj[i + eg];
                const uint4 u0 = *(const uint4*)(x1b + (p0 & 0x0FFFFF00) + dl * 16);
                UNPACK_ACC(p0, u0);
                i += 4;
            }
            if (i < end) {
                const int ig = i + eg;
                if (ig < end) {
                    const int p0 = adj[ig];
                    const uint4 u0 = *(const uint4*)(x1b + (p0 & 0x0FFFFF00) + dl * 16);
                    UNPACK_ACC(p0, u0);
                }
            }
#pragma unroll
            for (int k = 0; k < 8; k++) { a0[k] += __shfl_xor(a0[k], 16); a1[k] += __shfl_xor(a1[k], 16); }
#pragma unroll
            for (int k = 0; k < 8; k++) { a0[k] += __shfl_xor(a0[k], 32); a1[k] += __shfl_xor(a1[k], 32); }
            const int c0 = cnt[n * 2], c1 = cnt[n * 2 + 1];
            const float s0 = c0 > 0 ? 1.f / (float)c0 : 0.f;
            const float s1 = c1 > 0 ? 1.f / (float)c1 : 0.f;
            if (eg == 0) {
#pragma unroll
                for (int k = 0; k < 8; k++) As[r][dl * 8 + k] = a0[k] * s0;
            } else if (eg == 1) {
#pragma unroll
                for (int k = 0; k < 8; k++) As[r][128 + dl * 8 + k] = a1[k] * s1;
            } else if (eg == 2) {
                const uint4 ux = *(const uint4*)(x1 + (size_t)n * 128 + dl * 8);
                As[r][256 + dl * 8 + 0] = __uint_as_float(ux.x << 16);
                As[r][256 + dl * 8 + 1] = __uint_as_float(ux.x & 0xFFFF0000u);
                As[r][256 + dl * 8 + 2] = __uint_as_float(ux.y << 16);
                As[r][256 + dl * 8 + 3] = __uint_as_float(ux.y & 0xFFFF0000u);
                As[r][256 + dl * 8 + 4] = __uint_as_float(ux.z << 16);
                As[r][256 + dl * 8 + 5] = __uint_as_float(ux.z & 0xFFFF0000u);
                As[r][256 + dl * 8 + 6] = __uint_as_float(ux.w << 16);
                As[r][256 + dl * 8 + 7] = __uint_as_float(ux.w & 0xFFFF0000u);
            }
        }
    }
    __syncthreads();

    // ---- phase 2: gemm 16x384 @ 384x64 ----
    {
        const int o = tid & 63;
        const int q = tid >> 6;
        float acc[4] = {0.f, 0.f, 0.f, 0.f};
        for (int k = 0; k < 384; k += 4) {
            const float w0 = Wst[(k + 0) * 64 + o];
            const float w1_ = Wst[(k + 1) * 64 + o];
            const float w2_ = Wst[(k + 2) * 64 + o];
            const float w3_ = Wst[(k + 3) * 64 + o];
#pragma unroll
            for (int rr = 0; rr < 4; rr++) {
                const float4 a = *(const float4*)&As[q * 4 + rr][k];
                acc[rr] = fmaf(a.x, w0, acc[rr]);
                acc[rr] = fmaf(a.y, w1_, acc[rr]);
                acc[rr] = fmaf(a.z, w2_, acc[rr]);
                acc[rr] = fmaf(a.w, w3_, acc[rr]);
            }
        }
        const float bb = bias[o];
#pragma unroll
        for (int rr = 0; rr < 4; rr++) x2s[q * 4 + rr][o] = acc[rr] + bb;
    }
    __syncthreads();

    // ---- phase 3: MLP head, wave w handles rows w*4..w*4+3 ----
    for (int rr = 0; rr < 4; rr++) {
        const int r = w * 4 + rr;
        const int i = row0 + r;
        if (i >= B) continue;
        const int t = lane;
        const int tt = lane & 31;
        float e = x2s[r][t];
        outExpert[(size_t)i * 64 + t] = e;

        float y = b1[t];
#pragma unroll
        for (int k = 0; k < 64; k++) y = fmaf(__shfl(e, k), W1[k * 64 + t], y);
        float s = y;
        for (int off = 32; off; off >>= 1) s += __shfl_xor(s, off);
        float m = s * (1.f / 64.f);
        float d = y - m;
        float vs = d * d;
        for (int off = 32; off; off >>= 1) vs += __shfl_xor(vs, off);
        float h1 = fmaxf(fmaf(g1[t] * d, rsqrtf(vs * (1.f / 64.f) + 1e-5f), be1[t]), 0.f);

        float y2 = b2[tt];
#pragma unroll
        for (int k = 0; k < 64; k++) y2 = fmaf(__shfl(h1, k), W2[k * 32 + tt], y2);
        float s2 = y2;
        for (int off = 16; off; off >>= 1) s2 += __shfl_xor(s2, off);
        float m2 = s2 * (1.f / 32.f);
        float d2 = y2 - m2;
        float v2 = d2 * d2;
        for (int off = 16; off; off >>= 1) v2 += __shfl_xor(v2, off);
        float h2 = fmaxf(fmaf(g2[tt] * d2, rsqrtf(v2 * (1.f / 32.f) + 1e-5f), be2[tt]), 0.f);

        float p = h2 * W3[tt];
        for (int off = 16; off; off >>= 1) p += __shfl_xor(p, off);
        if (t == 0) outProb[i] = 1.f / (1.f + expf(-(p + b3[0])));
    }
}

extern "C" void kernel_launch(void* const* d_in, const int* in_sizes, int n_in,
                              void* d_out, int out_size, void* d_ws, size_t ws_size,
                              hipStream_t stream) {
    const int*   node_indices = (const int*)d_in[0];
    const int*   edge_index   = (const int*)d_in[1];
    const int*   edge_type    = (const int*)d_in[2];
    const float* x_feat       = (const float*)d_in[3];
    const float* basis0       = (const float*)d_in[4];
    const float* comp0        = (const float*)d_in[5];
    const float* root0        = (const float*)d_in[6];
    const float* bias0        = (const float*)d_in[7];
    const float* basis1       = (const float*)d_in[8];
    const float* comp1        = (const float*)d_in[9];
    const float* root1        = (const float*)d_in[10];
    const float* bias1        = (const float*)d_in[11];
    const float* W1 = (const float*)d_in[12];
    const float* b1 = (const float*)d_in[13];
    const float* g1 = (const float*)d_in[14];
    const float* be1 = (const float*)d_in[15];
    const float* W2 = (const float*)d_in[16];
    const float* b2 = (const float*)d_in[17];
    const float* g2 = (const float*)d_in[18];
    const float* be2 = (const float*)d_in[19];
    const float* W3 = (const float*)d_in[20];
    const float* b3 = (const float*)d_in[21];

    const int B = in_sizes[0];
    const int E = in_sizes[1] / 2;
    const int* src = edge_index;
    const int* dst = edge_index + E;
    const int nblk = (E + EPB - 1) / EPB;   // 782 for E=1.6M

    // ---- workspace carve-out (256B aligned) ----
    size_t off = 0;
    auto alloc = [&](size_t sz) { size_t o = off; off = (off + sz + 255) & ~(size_t)255; return o; };
    char* ws = (char*)d_ws;
    ushort* xb    = (ushort*)(ws + alloc((size_t)N_NODES * 128 * 2));
    ushort* Amat  = (ushort*)(ws + alloc((size_t)N_NODES * 256 * 2));
    ushort* x1b   = (ushort*)(ws + alloc((size_t)N_NODES * 128 * 2));
    int*   cnt    = (int*)  (ws + alloc((size_t)N_NODES * 2 * 4));
    int*   rowptr = (int*)  (ws + alloc((size_t)(N_NODES + 1) * 4));
    int*   adj    = (int*)  (ws + alloc((size_t)E * 4));
    int*   tmp    = (int*)  (ws + alloc((size_t)E * 4));
    int*   blockHist  = (int*)(ws + alloc((size_t)nblk * NBUCK * 4));
    int*   bucketCnt  = (int*)(ws + alloc((size_t)NBUCK * 4));
    int*   bucketBase = (int*)(ws + alloc((size_t)NBUCK * 4));
    int*   mark     = (int*)(ws + alloc((size_t)N_NODES * 4));
    int*   nodeList = (int*)(ws + alloc((size_t)N_NODES * 4));
    int*   nodeCnt  = (int*)(ws + alloc(256));
    ushort* Wt0b  = (ushort*)(ws + alloc((size_t)128 * 384 * 2));
    float* Wst1   = (float*)(ws + alloc((size_t)384 * 64 * 4));

    float* outExpert = (float*)d_out;
    float* outProb   = (float*)d_out + (size_t)B * 64;

    // ---- merged hist + prep + zero (no memsets) ----
    prepA_kernel<<<nblk + NBX + 192 + 96 + NZB, 256, 0, stream>>>(dst, blockHist, E, nblk,
                                                                  x_feat, xb, basis0, comp0, root0, Wt0b,
                                                                  basis1, comp1, root1, Wst1,
                                                                  mark, nodeCnt);

    // ---- CSR build (atomic-free bases; parallel scans) ----
    cscan_kernel<<<NBUCK, 256, 0, stream>>>(blockHist, nblk, bucketCnt);
    bscan2_kernel<<<1, 512, 0, stream>>>(bucketCnt, bucketBase, rowptr, E);
    binB_kernel<<<nblk, 256, 0, stream>>>(src, dst, edge_type, blockHist, bucketBase, tmp, E);
    binC_kernel<<<NBUCK, 256, 0, stream>>>(tmp, bucketBase, bucketCnt, adj, cnt, rowptr);

    // ---- mark + compact needed nodes ----
    mark_kernel<<<((size_t)B * 64 + 255) / 256, 256, 0, stream>>>(node_indices, rowptr, adj, mark, B);
    compact_kernel<<<NBUCK, 256, 0, stream>>>(mark, nodeList, nodeCnt);

    // ---- layer 0 (marked nodes only) ----
    gather0_kernel<<<(N_NODES * 64 + 255) / 256, 256, 0, stream>>>(nodeList, nodeCnt, rowptr, adj, cnt, xb, Amat);
    gemm0_kernel<<<(N_NODES + BM - 1) / BM, 256, 0, stream>>>(Amat, xb, nodeList, nodeCnt, Wt0b, bias0, x1b);

    // ---- layer 1 + head (fused) ----
    tail_kernel<<<(B + 15) / 16, 256, 0, stream>>>(node_indices, rowptr, adj, cnt, x1b,
                                                   Wst1, bias1,
                                                   W1, b1, g1, be1, W2, b2, g2, be2, W3, b3,
                                                   outExpert, outProb, B);
}